// Round 9
// baseline (318.791 us; speedup 1.0000x reference)
//
#include <hip/hip_runtime.h>
#include <hip/hip_bf16.h>

#define NN 131072
#define NE 1048576

typedef unsigned short u16;
typedef unsigned int u32;
typedef float f4v __attribute__((ext_vector_type(4)));
typedef unsigned int u4v __attribute__((ext_vector_type(4)));

__device__ __forceinline__ float bf2f(u16 u) {
  return __uint_as_float(((unsigned int)u) << 16);
}
__device__ __forceinline__ u16 f2bf(float f) {
  unsigned int u = __float_as_uint(f);
  unsigned int r = ((u >> 16) & 1u) + 0x7fffu;
  return (u16)((u + r) >> 16);
}
__device__ __forceinline__ float leakyf(float x) { return x >= 0.f ? x : 0.2f * x; }

// ---------------- workspace layout (bytes, all 16B-aligned) ----------------
constexpr size_t OFF_H1   = 0;                        // bf16 N*64 (raw)
constexpr size_t OFF_AS1N = 16777216;                 // f32 N*8 (raw)
constexpr size_t OFF_AD1N = 20971520;                 // f32 N*8 (raw)
constexpr size_t OFF_ZS   = 25165824;                 // float2 N {as2n, z}
constexpr size_t OFF_AD2N = 26214400;                 // f32 N
constexpr size_t OFF_RP   = 26738688;                 // int N+1
constexpr size_t OFF_WOFF = 27264000;                 // int N
constexpr size_t OFF_COL  = 27788288;                 // int E
constexpr size_t OFF_MP   = 31982592;                 // f32 M'[80][128]
constexpr size_t OFF_C1AC = 32023552;                 // f32 c1[64], ac[8]
constexpr size_t OFF_V2   = 32023840;                 // f32 va,vd,vz[64ea], cconst
constexpr size_t OFF_BSUM = 32024624;                 // int 128

// ---------------- scans ----------------
__global__ __launch_bounds__(1024) void scanA_kernel(const int* cnt, int* rp, int* bsum) {
  __shared__ int buf[1024];
  int t = threadIdx.x;
  int i = blockIdx.x * 1024 + t;
  int v = cnt[i];
  buf[t] = v;
  __syncthreads();
  for (int off = 1; off < 1024; off <<= 1) {
    int a = (t >= off) ? buf[t - off] : 0;
    __syncthreads();
    buf[t] += a;
    __syncthreads();
  }
  rp[i] = buf[t] - v;  // block-local exclusive
  if (t == 1023) bsum[blockIdx.x] = buf[t];
}
__global__ void scanB_kernel(int* bsum, int* rp) {
  __shared__ int buf[128];
  int t = threadIdx.x;
  int v = bsum[t];
  buf[t] = v;
  __syncthreads();
  for (int off = 1; off < 128; off <<= 1) {
    int a = (t >= off) ? buf[t - off] : 0;
    __syncthreads();
    buf[t] += a;
    __syncthreads();
  }
  bsum[t] = buf[t] - v;  // exclusive block offsets
  if (t == 127) rp[NN] = buf[127];
}
__global__ __launch_bounds__(1024) void scanC_kernel(int* rp, const int* bsum, int* wo) {
  int i = blockIdx.x * 1024 + threadIdx.x;
  int v = rp[i] + bsum[blockIdx.x];
  rp[i] = v;
  wo[i] = v;
}

// ======== fused: count (XCD-partitioned) || M'[80][128] fold || c1/ac || v2 ========
// blocks [0,4096): count; [4096,4136): M' rows; 4136: c1+ac; 4137: v2 (fold2).
__global__ __launch_bounds__(256) void count_fold_kernel(
    const int* __restrict__ ei, int* cnt, const float* W1, const float* We,
    const float* be, const float* bng, const float* bnb, const float* bnm,
    const float* bnv, const float* as1, const float* ad1, const float* W2,
    const float* as2, const float* ad2, const float* Wo, const float* b2,
    const float* bo, float* MP, float* c1ac, float* v2) {
  int b = blockIdx.x;
  int t = threadIdx.x;
  if (b < 4096) {
    // count: block only handles dst in partition b%8 (dst>>14) -> atomics stay on one XCD.
    // nt loads: ei is pure stream, keep L2 for the cnt lines.
    int p = b & 7;
    int base = (b >> 3) * 2048;
    for (int i = t; i < 2048; i += 256) {
      int dst = __builtin_nontemporal_load(ei + NE + base + i);
      if ((dst >> 14) == p) atomicAdd(&cnt[dst], 1);
    }
  } else if (b < 4136) {
    // M' rows: M1 (rows<64) or A1/D1 (rows 64..79), all = L·diag(sg)·We form
    __shared__ float L[2][256];
    int mrow = b - 4096;
    int r0 = mrow * 2;
    int lr = t >> 7, k = t & 127;
    float sgc = bng[t] * rsqrtf(bnv[t] + 1e-5f);
#pragma unroll
    for (int q = 0; q < 2; ++q) {
      int r = r0 + q;
      float coef;
      if (r < 64) {
        coef = W1[r * 256 + t];
      } else if (r < 72) {
        int h = r - 64;
        coef = 0.f;
#pragma unroll
        for (int j = 0; j < 8; ++j) coef += as1[h * 8 + j] * W1[(h * 8 + j) * 256 + t];
      } else {
        int h = r - 72;
        coef = 0.f;
#pragma unroll
        for (int j = 0; j < 8; ++j) coef += ad1[h * 8 + j] * W1[(h * 8 + j) * 256 + t];
      }
      L[q][t] = coef * sgc;
    }
    __syncthreads();
    float acc = 0.f;
    for (int c = 0; c < 256; ++c) acc += L[lr][c] * We[c * 128 + k];
    MP[(size_t)(r0 + lr) * 128 + k] = acc;
  } else if (b == 4136) {
    // c1 = W1·ofs ; ac[h] = sum_j c1[h*8+j]*(as1+ad1)
    __shared__ float ofs[256];
    __shared__ float c1l[64];
    float sgc = bng[t] * rsqrtf(bnv[t] + 1e-5f);
    ofs[t] = (be[t] - bnm[t]) * sgc + bnb[t];
    __syncthreads();
    if (t < 64) {
      float a = 0.f;
      for (int c = 0; c < 256; ++c) a += W1[t * 256 + c] * ofs[c];
      c1ac[t] = a;
      c1l[t] = a;
    }
    __syncthreads();
    if (t < 8) {
      float s = 0.f;
#pragma unroll
      for (int j = 0; j < 8; ++j) s += c1l[t * 8 + j] * (as1[t * 8 + j] + ad1[t * 8 + j]);
      c1ac[64 + t] = s;
    }
  } else {
    // v2: va = W2^T as2, vd = W2^T ad2, vz = W2^T Wo, cconst = b2.Wo + bo
    __shared__ float pa[4][64], pd[4][64], pz[4][64];
    int k = t & 63, part = t >> 6;
    float a = 0.f, d = 0.f, z = 0.f;
    for (int c = part * 64; c < part * 64 + 64; ++c) {
      float w = W2[c * 64 + k];
      a += as2[c] * w;
      d += ad2[c] * w;
      z += Wo[c] * w;
    }
    pa[part][k] = a;
    pd[part][k] = d;
    pz[part][k] = z;
    __syncthreads();
    if (t < 64) {
      v2[t]       = pa[0][t] + pa[1][t] + pa[2][t] + pa[3][t];
      v2[64 + t]  = pd[0][t] + pd[1][t] + pd[2][t] + pd[3][t];
      v2[128 + t] = pz[0][t] + pz[1][t] + pz[2][t] + pz[3][t];
      float cc = b2[t] * Wo[t] + b2[64 + t] * Wo[64 + t] +
                 b2[128 + t] * Wo[128 + t] + b2[192 + t] * Wo[192 + t];
      for (int o = 1; o < 64; o <<= 1) cc += __shfl_xor(cc, o);
      if (t == 0) v2[192] = cc + bo[0];
    }
  }
}

// ======== fused: gemm_h1 (blocks 0..511) || fill (blocks 512..4607) ========
// gemm side is pure streaming (x in, h1/as1n/ad1n out) -> ALL non-temporal, so
// L2 stays dedicated to fill's colv/wo lines (write-merge intact).
__global__ __launch_bounds__(256) void fill_gemm_kernel(const float* __restrict__ x,
                                                        const float* __restrict__ MP,
                                                        u16* __restrict__ h1,
                                                        float* __restrict__ as1n,
                                                        float* __restrict__ ad1n,
                                                        const int* __restrict__ ei,
                                                        int* wo, int* colv) {
  __shared__ float4 sM[80 * 32];
  int b = blockIdx.x;
  int t = threadIdx.x;
  if (b >= 512) {
    // ---- fill (XCD-partitioned), nt loads of the ei streams ----
    int fb = b - 512;
    int p = fb & 7;
    int base = (fb >> 3) * 2048;
    for (int i = t; i < 2048; i += 256) {
      int e = base + i;
      int dst = __builtin_nontemporal_load(ei + NE + e);
      if ((dst >> 14) == p) {
        int pos = atomicAdd(&wo[dst], 1);
        colv[pos] = __builtin_nontemporal_load(ei + e);
      }
    }
    return;
  }
  // ---- gemm: h1' = x @ M'^T, M' = [M1;A1;D1] (80x128), LDS-broadcast M' ----
  int lane = t & 63, wv = t >> 6;
  const float4* MPv = (const float4*)MP;
  for (int i = t; i < 2560; i += 256) sM[i] = MPv[i];
  __syncthreads();
  int c0 = (wv & 1) * 40;  // col half
  size_t r0 = (size_t)b * 256 + (wv >> 1) * 128 + lane;  // rows r0, r0+64
  const f4v* x0 = (const f4v*)(x + r0 * 128);
  const f4v* x1 = (const f4v*)(x + (r0 + 64) * 128);
  float a0[40], a1[40];
#pragma unroll
  for (int c = 0; c < 40; ++c) { a0[c] = 0.f; a1[c] = 0.f; }
  for (int q = 0; q < 32; ++q) {
    f4v cx0 = __builtin_nontemporal_load(x0 + q);
    f4v cx1 = __builtin_nontemporal_load(x1 + q);
    const float4* mp = sM + c0 * 32 + q;
#pragma unroll
    for (int c = 0; c < 40; ++c) {
      float4 B = mp[c * 32];
      a0[c] += cx0.x * B.x; a0[c] += cx0.y * B.y;
      a0[c] += cx0.z * B.z; a0[c] += cx0.w * B.w;
      a1[c] += cx1.x * B.x; a1[c] += cx1.y * B.y;
      a1[c] += cx1.z * B.z; a1[c] += cx1.w * B.w;
    }
  }
#pragma unroll
  for (int rr = 0; rr < 2; ++rr) {
    size_t row = r0 + rr * 64;
    if (c0 == 0) {
      u32 ux[20];
#pragma unroll
      for (int j = 0; j < 20; ++j) {
        float lo = rr ? a1[2 * j] : a0[2 * j];
        float hi = rr ? a1[2 * j + 1] : a0[2 * j + 1];
        ux[j] = (u32)f2bf(lo) | ((u32)f2bf(hi) << 16);
      }
      u4v* dst = (u4v*)(h1 + row * 64);
#pragma unroll
      for (int j = 0; j < 5; ++j) {
        u4v vv = {ux[4 * j], ux[4 * j + 1], ux[4 * j + 2], ux[4 * j + 3]};
        __builtin_nontemporal_store(vv, dst + j);
      }
    } else {
      u32 ux[12];
#pragma unroll
      for (int j = 0; j < 12; ++j) {
        float lo = rr ? a1[2 * j] : a0[2 * j];
        float hi = rr ? a1[2 * j + 1] : a0[2 * j + 1];
        ux[j] = (u32)f2bf(lo) | ((u32)f2bf(hi) << 16);
      }
      u4v* dst = (u4v*)(h1 + row * 64 + 40);
#pragma unroll
      for (int j = 0; j < 3; ++j) {
        u4v vv = {ux[4 * j], ux[4 * j + 1], ux[4 * j + 2], ux[4 * j + 3]};
        __builtin_nontemporal_store(vv, dst + j);
      }
      f4v* as4 = (f4v*)(as1n + row * 8);
      f4v* ad4 = (f4v*)(ad1n + row * 8);
      if (rr == 0) {
        f4v s0 = {a0[24], a0[25], a0[26], a0[27]};
        f4v s1 = {a0[28], a0[29], a0[30], a0[31]};
        f4v d0 = {a0[32], a0[33], a0[34], a0[35]};
        f4v d1 = {a0[36], a0[37], a0[38], a0[39]};
        __builtin_nontemporal_store(s0, as4);
        __builtin_nontemporal_store(s1, as4 + 1);
        __builtin_nontemporal_store(d0, ad4);
        __builtin_nontemporal_store(d1, ad4 + 1);
      } else {
        f4v s0 = {a1[24], a1[25], a1[26], a1[27]};
        f4v s1 = {a1[28], a1[29], a1[30], a1[31]};
        f4v d0 = {a1[32], a1[33], a1[34], a1[35]};
        f4v d1 = {a1[36], a1[37], a1[38], a1[39]};
        __builtin_nontemporal_store(s0, as4);
        __builtin_nontemporal_store(s1, as4 + 1);
        __builtin_nontemporal_store(d0, ad4);
        __builtin_nontemporal_store(d1, ad4 + 1);
      }
    }
  }
}

// ------ GAT1 aggregation + ELU + fused GAT2 node scalars (packed-pair form) ------
__global__ __launch_bounds__(256) void gat1_agg_kernel(const int* __restrict__ rp,
                                                       const int* __restrict__ colv,
                                                       const float* __restrict__ as1n,
                                                       const float* __restrict__ ad1n,
                                                       const u16* __restrict__ h1,
                                                       const float* b1,
                                                       const float* __restrict__ c1ac,
                                                       const float* v2,
                                                       float2* zs, float* ad2n) {
  __shared__ float wlds[4][64];
  __shared__ int slds[4][8];
  int t = threadIdx.x, lane = t & 63, wv = t >> 6;
  int n = blockIdx.x * 4 + wv;
  int m = lane & 31;    // channel pair (2m, 2m+1)
  int half = lane >> 5; // edge parity this lane accumulates
  int hh = m >> 2;      // head of channels 2m,2m+1
  int h1i = lane & 7;   // phase-1 head
  int e8 = lane >> 3;   // phase-1 edge slot
  int start = rp[n], end = rp[n + 1];
  const char* h1b = (const char*)h1;
  float adh = ad1n[(size_t)n * 8 + hh] + c1ac[64 + hh];
  float ws = __expf(leakyf(as1n[(size_t)n * 8 + hh] + adh));
  float denom = ws;
  u32 sv = *(const u32*)(h1b + ((size_t)n << 7) + m * 4);
  float wsel = half ? 0.f : ws;  // self-loop only in half 0
  float acc0 = wsel * __uint_as_float(sv << 16);
  float acc1 = wsel * __uint_as_float(sv & 0xffff0000u);
  float ad_p1 = ad1n[(size_t)n * 8 + h1i] + c1ac[64 + h1i];  // phase-1 layout
  for (int base = start; base < end; base += 8) {
    int mm = end - base;
    if (mm > 8) mm = 8;
    // ---- phase 1: weights for 8 edges x 8 heads ----
    int eidx = base + e8;
    int ecl = (eidx < end) ? eidx : (end - 1);
    int s = colv[ecl];
    float w = (e8 < mm) ? __expf(leakyf(as1n[(size_t)s * 8 + h1i] + ad_p1)) : 0.f;
    if (h1i == 0) slds[wv][e8] = s;
    wlds[wv][lane] = w;
    float dsum = w;
    dsum += __shfl_xor(dsum, 8);
    dsum += __shfl_xor(dsum, 16);
    dsum += __shfl_xor(dsum, 32);
    denom += __shfl(dsum, hh);
    // ---- phase 2: 2 edges per iteration (half 0: even, half 1: odd) ----
#pragma unroll
    for (int i = 0; i < 4; ++i) {
      int e = 2 * i + half;
      float wi = wlds[wv][e * 8 + hh];
      int si = slds[wv][e];
      u32 v = *(const u32*)(h1b + ((size_t)si << 7) + m * 4);
      acc0 += wi * __uint_as_float(v << 16);
      acc1 += wi * __uint_as_float(v & 0xffff0000u);
    }
  }
  acc0 += __shfl_xor(acc0, 32);
  acc1 += __shfl_xor(acc1, 32);
  float dinv = __builtin_amdgcn_rcpf(denom + 1e-16f);
  float2 c1p = ((const float2*)c1ac)[m];
  float2 b1p = ((const float2*)b1)[m];
  float v0 = acc0 * dinv + c1p.x + b1p.x;
  float v1 = acc1 * dinv + c1p.y + b1p.y;
  v0 = v0 > 0.f ? v0 : __expf(v0) - 1.f;  // ELU
  v1 = v1 > 0.f ? v1 : __expf(v1) - 1.f;
  float2 vap = ((const float2*)v2)[m];
  float2 vdp = ((const float2*)(v2 + 64))[m];
  float2 vzp = ((const float2*)(v2 + 128))[m];
  float p0 = v0 * vap.x + v1 * vap.y;
  float p1 = v0 * vdp.x + v1 * vdp.y;
  float p2 = v0 * vzp.x + v1 * vzp.y;
  for (int o = 1; o < 32; o <<= 1) {
    p0 += __shfl_xor(p0, o);
    p1 += __shfl_xor(p1, o);
    p2 += __shfl_xor(p2, o);
  }
  if (lane == 0) {
    zs[n] = make_float2(p0, p2);
    ad2n[n] = p1;
  }
}

// ------- GAT2 scalar aggregation: 8 lanes per node -------
__global__ __launch_bounds__(256) void gat2_kernel(const int* __restrict__ rp,
                                                   const int* __restrict__ colv,
                                                   const float2* __restrict__ zs,
                                                   const float* __restrict__ ad2n,
                                                   const float* v2, float* out) {
  int t = threadIdx.x;
  int g = t & 7;
  int n = blockIdx.x * 32 + (t >> 3);
  int start = rp[n], end = rp[n + 1];
  float ad = ad2n[n];
  float num = 0.f, den = 0.f;
  for (int e = start + g; e < end; e += 8) {
    int s = colv[e];
    float2 tt = zs[s];
    float wi = __expf(leakyf(tt.x + ad));
    num += wi * tt.y;
    den += wi;
  }
  if (g == 0) {
    float2 self = zs[n];
    float w = __expf(leakyf(self.x + ad));
    num += w * self.y;
    den += w;
  }
  num += __shfl_xor(num, 1); den += __shfl_xor(den, 1);
  num += __shfl_xor(num, 2); den += __shfl_xor(den, 2);
  num += __shfl_xor(num, 4); den += __shfl_xor(den, 4);
  if (g == 0) {
    out[n] = num * __builtin_amdgcn_rcpf(den + 1e-16f) + v2[192];
    out[NN + n] = 0.f;
  }
}

extern "C" void kernel_launch(void* const* d_in, const int* in_sizes, int n_in,
                              void* d_out, int out_size, void* d_ws, size_t ws_size,
                              hipStream_t stream) {
  const float* x   = (const float*)d_in[0];
  const int*   ei  = (const int*)d_in[1];
  const float* We  = (const float*)d_in[2];
  const float* be  = (const float*)d_in[3];
  const float* bng = (const float*)d_in[4];
  const float* bnb = (const float*)d_in[5];
  const float* bnm = (const float*)d_in[6];
  const float* bnv = (const float*)d_in[7];
  const float* W1  = (const float*)d_in[8];
  const float* as1 = (const float*)d_in[9];
  const float* ad1 = (const float*)d_in[10];
  const float* b1  = (const float*)d_in[11];
  const float* W2  = (const float*)d_in[12];
  const float* as2 = (const float*)d_in[13];
  const float* ad2 = (const float*)d_in[14];
  const float* b2  = (const float*)d_in[15];
  const float* Wo  = (const float*)d_in[16];
  const float* bo  = (const float*)d_in[17];
  float* out = (float*)d_out;

  char* ws = (char*)d_ws;
  u16*    h1   = (u16*)(ws + OFF_H1);
  float*  as1n = (float*)(ws + OFF_AS1N);
  float*  ad1n = (float*)(ws + OFF_AD1N);
  float2* zs   = (float2*)(ws + OFF_ZS);
  float*  ad2n = (float*)(ws + OFF_AD2N);
  int*    rp   = (int*)(ws + OFF_RP);
  int*    wo   = (int*)(ws + OFF_WOFF);
  int*    colv = (int*)(ws + OFF_COL);
  float*  MP   = (float*)(ws + OFF_MP);
  float*  c1ac = (float*)(ws + OFF_C1AC);
  float*  v2   = (float*)(ws + OFF_V2);
  int*    bsum = (int*)(ws + OFF_BSUM);

  hipMemsetAsync(wo, 0, NN * sizeof(int), stream);
  count_fold_kernel<<<4138, 256, 0, stream>>>(ei, wo, W1, We, be, bng, bnb, bnm, bnv,
                                              as1, ad1, W2, as2, ad2, Wo, b2, bo,
                                              MP, c1ac, v2);
  scanA_kernel<<<NN / 1024, 1024, 0, stream>>>(wo, rp, bsum);
  scanB_kernel<<<1, 128, 0, stream>>>(bsum, rp);
  scanC_kernel<<<NN / 1024, 1024, 0, stream>>>(rp, bsum, wo);
  fill_gemm_kernel<<<4608, 256, 0, stream>>>(x, MP, h1, as1n, ad1n, ei, wo, colv);
  gat1_agg_kernel<<<NN / 4, 256, 0, stream>>>(rp, colv, as1n, ad1n, h1, b1, c1ac, v2, zs, ad2n);
  gat2_kernel<<<NN / 32, 256, 0, stream>>>(rp, colv, zs, ad2n, v2, out);
}

// Round 10
// 264.459 us; speedup vs baseline: 1.2054x; 1.2054x over previous
//
#include <hip/hip_runtime.h>
#include <hip/hip_bf16.h>

#define NN 131072
#define NE 1048576

typedef unsigned short u16;
typedef unsigned int u32;

__device__ __forceinline__ float bf2f(u16 u) {
  return __uint_as_float(((unsigned int)u) << 16);
}
__device__ __forceinline__ u16 f2bf(float f) {
  unsigned int u = __float_as_uint(f);
  unsigned int r = ((u >> 16) & 1u) + 0x7fffu;
  return (u16)((u + r) >> 16);
}
__device__ __forceinline__ float leakyf(float x) { return x >= 0.f ? x : 0.2f * x; }

// ---------------- workspace layout (bytes, all 16B-aligned) ----------------
constexpr size_t OFF_H1   = 0;                        // bf16 N*64 (raw)
constexpr size_t OFF_AS1N = 16777216;                 // f32 N*8 (raw)
constexpr size_t OFF_AD1N = 20971520;                 // f32 N*8 (raw)
constexpr size_t OFF_ZS   = 25165824;                 // float2 N {as2n, z}
constexpr size_t OFF_AD2N = 26214400;                 // f32 N
constexpr size_t OFF_RP   = 26738688;                 // int N+1
constexpr size_t OFF_WOFF = 27264000;                 // int N
constexpr size_t OFF_COL  = 27788288;                 // int E
constexpr size_t OFF_MP   = 31982592;                 // f32 M'[80][128]
constexpr size_t OFF_C1AC = 32023552;                 // f32 c1[64], ac[8]
constexpr size_t OFF_V2   = 32023840;                 // f32 va,vd,vz[64ea], cconst
constexpr size_t OFF_BSUM = 32024624;                 // int 128

// ---------------- scans ----------------
__global__ __launch_bounds__(1024) void scanA_kernel(const int* cnt, int* rp, int* bsum) {
  __shared__ int buf[1024];
  int t = threadIdx.x;
  int i = blockIdx.x * 1024 + t;
  int v = cnt[i];
  buf[t] = v;
  __syncthreads();
  for (int off = 1; off < 1024; off <<= 1) {
    int a = (t >= off) ? buf[t - off] : 0;
    __syncthreads();
    buf[t] += a;
    __syncthreads();
  }
  rp[i] = buf[t] - v;  // block-local exclusive
  if (t == 1023) bsum[blockIdx.x] = buf[t];
}
__global__ void scanB_kernel(int* bsum, int* rp) {
  __shared__ int buf[128];
  int t = threadIdx.x;
  int v = bsum[t];
  buf[t] = v;
  __syncthreads();
  for (int off = 1; off < 128; off <<= 1) {
    int a = (t >= off) ? buf[t - off] : 0;
    __syncthreads();
    buf[t] += a;
    __syncthreads();
  }
  bsum[t] = buf[t] - v;  // exclusive block offsets
  if (t == 127) rp[NN] = buf[127];
}
__global__ __launch_bounds__(1024) void scanC_kernel(int* rp, const int* bsum, int* wo) {
  int i = blockIdx.x * 1024 + threadIdx.x;
  int v = rp[i] + bsum[blockIdx.x];
  rp[i] = v;
  wo[i] = v;
}

// ======== fused: count (XCD-partitioned) || M'[80][128] fold || c1/ac || v2 ========
// blocks [0,4096): count; [4096,4136): M' rows; 4136: c1+ac; 4137: v2 (fold2).
__global__ __launch_bounds__(256) void count_fold_kernel(
    const int* __restrict__ ei, int* cnt, const float* W1, const float* We,
    const float* be, const float* bng, const float* bnb, const float* bnm,
    const float* bnv, const float* as1, const float* ad1, const float* W2,
    const float* as2, const float* ad2, const float* Wo, const float* b2,
    const float* bo, float* MP, float* c1ac, float* v2) {
  int b = blockIdx.x;
  int t = threadIdx.x;
  if (b < 4096) {
    // count: block only handles dst in partition b%8 (dst>>14) -> atomics stay on one XCD
    int p = b & 7;
    int base = (b >> 3) * 2048;
    for (int i = t; i < 2048; i += 256) {
      int dst = ei[NE + base + i];
      if ((dst >> 14) == p) atomicAdd(&cnt[dst], 1);
    }
  } else if (b < 4136) {
    // M' rows: M1 (rows<64) or A1/D1 (rows 64..79), all = L·diag(sg)·We form
    __shared__ float L[2][256];
    int mrow = b - 4096;
    int r0 = mrow * 2;
    int lr = t >> 7, k = t & 127;
    float sgc = bng[t] * rsqrtf(bnv[t] + 1e-5f);
#pragma unroll
    for (int q = 0; q < 2; ++q) {
      int r = r0 + q;
      float coef;
      if (r < 64) {
        coef = W1[r * 256 + t];
      } else if (r < 72) {
        int h = r - 64;
        coef = 0.f;
#pragma unroll
        for (int j = 0; j < 8; ++j) coef += as1[h * 8 + j] * W1[(h * 8 + j) * 256 + t];
      } else {
        int h = r - 72;
        coef = 0.f;
#pragma unroll
        for (int j = 0; j < 8; ++j) coef += ad1[h * 8 + j] * W1[(h * 8 + j) * 256 + t];
      }
      L[q][t] = coef * sgc;
    }
    __syncthreads();
    float acc = 0.f;
    for (int c = 0; c < 256; ++c) acc += L[lr][c] * We[c * 128 + k];
    MP[(size_t)(r0 + lr) * 128 + k] = acc;
  } else if (b == 4136) {
    // c1 = W1·ofs ; ac[h] = sum_j c1[h*8+j]*(as1+ad1)
    __shared__ float ofs[256];
    __shared__ float c1l[64];
    float sgc = bng[t] * rsqrtf(bnv[t] + 1e-5f);
    ofs[t] = (be[t] - bnm[t]) * sgc + bnb[t];
    __syncthreads();
    if (t < 64) {
      float a = 0.f;
      for (int c = 0; c < 256; ++c) a += W1[t * 256 + c] * ofs[c];
      c1ac[t] = a;
      c1l[t] = a;
    }
    __syncthreads();
    if (t < 8) {
      float s = 0.f;
#pragma unroll
      for (int j = 0; j < 8; ++j) s += c1l[t * 8 + j] * (as1[t * 8 + j] + ad1[t * 8 + j]);
      c1ac[64 + t] = s;
    }
  } else {
    // v2: va = W2^T as2, vd = W2^T ad2, vz = W2^T Wo, cconst = b2.Wo + bo
    __shared__ float pa[4][64], pd[4][64], pz[4][64];
    int k = t & 63, part = t >> 6;
    float a = 0.f, d = 0.f, z = 0.f;
    for (int c = part * 64; c < part * 64 + 64; ++c) {
      float w = W2[c * 64 + k];
      a += as2[c] * w;
      d += ad2[c] * w;
      z += Wo[c] * w;
    }
    pa[part][k] = a;
    pd[part][k] = d;
    pz[part][k] = z;
    __syncthreads();
    if (t < 64) {
      v2[t]       = pa[0][t] + pa[1][t] + pa[2][t] + pa[3][t];
      v2[64 + t]  = pd[0][t] + pd[1][t] + pd[2][t] + pd[3][t];
      v2[128 + t] = pz[0][t] + pz[1][t] + pz[2][t] + pz[3][t];
      float cc = b2[t] * Wo[t] + b2[64 + t] * Wo[64 + t] +
                 b2[128 + t] * Wo[128 + t] + b2[192 + t] * Wo[192 + t];
      for (int o = 1; o < 64; o <<= 1) cc += __shfl_xor(cc, o);
      if (t == 0) v2[192] = cc + bo[0];
    }
  }
}

// ======== fused: fill (blocks 0..4095, dispatched FIRST) || gemm_h1 (4096..4607) ========
// Fill-first ordering: the short fill blocks occupy the machine and complete
// (colv partial lines merge in a clean L2) before gemm streams x through.
__global__ __launch_bounds__(256) void fill_gemm_kernel(const float* __restrict__ x,
                                                        const float* __restrict__ MP,
                                                        u16* __restrict__ h1,
                                                        float* __restrict__ as1n,
                                                        float* __restrict__ ad1n,
                                                        const int* __restrict__ ei,
                                                        int* wo, int* colv) {
  __shared__ float4 sM[80 * 32];
  int b = blockIdx.x;
  int t = threadIdx.x;
  if (b < 4096) {
    // ---- fill (XCD-partitioned) ----
    int p = b & 7;
    int base = (b >> 3) * 2048;
    for (int i = t; i < 2048; i += 256) {
      int e = base + i;
      int dst = ei[NE + e];
      if ((dst >> 14) == p) {
        int pos = atomicAdd(&wo[dst], 1);
        colv[pos] = ei[e];
      }
    }
    return;
  }
  // ---- gemm: h1' = x @ M'^T, M' = [M1;A1;D1] (80x128), LDS-broadcast M' ----
  int gb = b - 4096;
  int lane = t & 63, wv = t >> 6;
  const float4* MPv = (const float4*)MP;
  for (int i = t; i < 2560; i += 256) sM[i] = MPv[i];
  __syncthreads();
  int c0 = (wv & 1) * 40;  // col half
  size_t r0 = (size_t)gb * 256 + (wv >> 1) * 128 + lane;  // rows r0, r0+64
  const float4* x0 = (const float4*)(x + r0 * 128);
  const float4* x1 = (const float4*)(x + (r0 + 64) * 128);
  float a0[40], a1[40];
#pragma unroll
  for (int c = 0; c < 40; ++c) { a0[c] = 0.f; a1[c] = 0.f; }
  for (int q = 0; q < 32; ++q) {
    float4 cx0 = x0[q];
    float4 cx1 = x1[q];
    const float4* mp = sM + c0 * 32 + q;
#pragma unroll
    for (int c = 0; c < 40; ++c) {
      float4 B = mp[c * 32];
      a0[c] += cx0.x * B.x; a0[c] += cx0.y * B.y;
      a0[c] += cx0.z * B.z; a0[c] += cx0.w * B.w;
      a1[c] += cx1.x * B.x; a1[c] += cx1.y * B.y;
      a1[c] += cx1.z * B.z; a1[c] += cx1.w * B.w;
    }
  }
#pragma unroll
  for (int rr = 0; rr < 2; ++rr) {
    size_t row = r0 + rr * 64;
    if (c0 == 0) {
      u32 ux[20];
#pragma unroll
      for (int j = 0; j < 20; ++j) {
        float lo = rr ? a1[2 * j] : a0[2 * j];
        float hi = rr ? a1[2 * j + 1] : a0[2 * j + 1];
        ux[j] = (u32)f2bf(lo) | ((u32)f2bf(hi) << 16);
      }
      uint4* dst = (uint4*)(h1 + row * 64);
#pragma unroll
      for (int j = 0; j < 5; ++j)
        dst[j] = make_uint4(ux[4 * j], ux[4 * j + 1], ux[4 * j + 2], ux[4 * j + 3]);
    } else {
      u32 ux[12];
#pragma unroll
      for (int j = 0; j < 12; ++j) {
        float lo = rr ? a1[2 * j] : a0[2 * j];
        float hi = rr ? a1[2 * j + 1] : a0[2 * j + 1];
        ux[j] = (u32)f2bf(lo) | ((u32)f2bf(hi) << 16);
      }
      uint4* dst = (uint4*)(h1 + row * 64 + 40);
#pragma unroll
      for (int j = 0; j < 3; ++j)
        dst[j] = make_uint4(ux[4 * j], ux[4 * j + 1], ux[4 * j + 2], ux[4 * j + 3]);
      float4* as4 = (float4*)(as1n + row * 8);
      float4* ad4 = (float4*)(ad1n + row * 8);
      if (rr == 0) {
        as4[0] = make_float4(a0[24], a0[25], a0[26], a0[27]);
        as4[1] = make_float4(a0[28], a0[29], a0[30], a0[31]);
        ad4[0] = make_float4(a0[32], a0[33], a0[34], a0[35]);
        ad4[1] = make_float4(a0[36], a0[37], a0[38], a0[39]);
      } else {
        as4[0] = make_float4(a1[24], a1[25], a1[26], a1[27]);
        as4[1] = make_float4(a1[28], a1[29], a1[30], a1[31]);
        ad4[0] = make_float4(a1[32], a1[33], a1[34], a1[35]);
        ad4[1] = make_float4(a1[36], a1[37], a1[38], a1[39]);
      }
    }
  }
}

// ------ GAT1 aggregation + ELU + fused GAT2 node scalars (packed-pair form) ------
__global__ __launch_bounds__(256) void gat1_agg_kernel(const int* __restrict__ rp,
                                                       const int* __restrict__ colv,
                                                       const float* __restrict__ as1n,
                                                       const float* __restrict__ ad1n,
                                                       const u16* __restrict__ h1,
                                                       const float* b1,
                                                       const float* __restrict__ c1ac,
                                                       const float* v2,
                                                       float2* zs, float* ad2n) {
  __shared__ float wlds[4][64];
  __shared__ int slds[4][8];
  int t = threadIdx.x, lane = t & 63, wv = t >> 6;
  int n = blockIdx.x * 4 + wv;
  int m = lane & 31;    // channel pair (2m, 2m+1)
  int half = lane >> 5; // edge parity this lane accumulates
  int hh = m >> 2;      // head of channels 2m,2m+1
  int h1i = lane & 7;   // phase-1 head
  int e8 = lane >> 3;   // phase-1 edge slot
  int start = rp[n], end = rp[n + 1];
  const char* h1b = (const char*)h1;
  float adh = ad1n[(size_t)n * 8 + hh] + c1ac[64 + hh];
  float ws = __expf(leakyf(as1n[(size_t)n * 8 + hh] + adh));
  float denom = ws;
  u32 sv = *(const u32*)(h1b + ((size_t)n << 7) + m * 4);
  float wsel = half ? 0.f : ws;  // self-loop only in half 0
  float acc0 = wsel * __uint_as_float(sv << 16);
  float acc1 = wsel * __uint_as_float(sv & 0xffff0000u);
  float ad_p1 = ad1n[(size_t)n * 8 + h1i] + c1ac[64 + h1i];  // phase-1 layout
  for (int base = start; base < end; base += 8) {
    int mm = end - base;
    if (mm > 8) mm = 8;
    // ---- phase 1: weights for 8 edges x 8 heads ----
    int eidx = base + e8;
    int ecl = (eidx < end) ? eidx : (end - 1);
    int s = colv[ecl];
    float w = (e8 < mm) ? __expf(leakyf(as1n[(size_t)s * 8 + h1i] + ad_p1)) : 0.f;
    if (h1i == 0) slds[wv][e8] = s;
    wlds[wv][lane] = w;
    float dsum = w;
    dsum += __shfl_xor(dsum, 8);
    dsum += __shfl_xor(dsum, 16);
    dsum += __shfl_xor(dsum, 32);
    denom += __shfl(dsum, hh);
    // ---- phase 2: 2 edges per iteration (half 0: even, half 1: odd) ----
#pragma unroll
    for (int i = 0; i < 4; ++i) {
      int e = 2 * i + half;
      float wi = wlds[wv][e * 8 + hh];
      int si = slds[wv][e];
      u32 v = *(const u32*)(h1b + ((size_t)si << 7) + m * 4);
      acc0 += wi * __uint_as_float(v << 16);
      acc1 += wi * __uint_as_float(v & 0xffff0000u);
    }
  }
  acc0 += __shfl_xor(acc0, 32);
  acc1 += __shfl_xor(acc1, 32);
  float dinv = __builtin_amdgcn_rcpf(denom + 1e-16f);
  float2 c1p = ((const float2*)c1ac)[m];
  float2 b1p = ((const float2*)b1)[m];
  float v0 = acc0 * dinv + c1p.x + b1p.x;
  float v1 = acc1 * dinv + c1p.y + b1p.y;
  v0 = v0 > 0.f ? v0 : __expf(v0) - 1.f;  // ELU
  v1 = v1 > 0.f ? v1 : __expf(v1) - 1.f;
  float2 vap = ((const float2*)v2)[m];
  float2 vdp = ((const float2*)(v2 + 64))[m];
  float2 vzp = ((const float2*)(v2 + 128))[m];
  float p0 = v0 * vap.x + v1 * vap.y;
  float p1 = v0 * vdp.x + v1 * vdp.y;
  float p2 = v0 * vzp.x + v1 * vzp.y;
  for (int o = 1; o < 32; o <<= 1) {
    p0 += __shfl_xor(p0, o);
    p1 += __shfl_xor(p1, o);
    p2 += __shfl_xor(p2, o);
  }
  if (lane == 0) {
    zs[n] = make_float2(p0, p2);
    ad2n[n] = p1;
  }
}

// ------- GAT2 scalar aggregation: 8 lanes per node -------
__global__ __launch_bounds__(256) void gat2_kernel(const int* __restrict__ rp,
                                                   const int* __restrict__ colv,
                                                   const float2* __restrict__ zs,
                                                   const float* __restrict__ ad2n,
                                                   const float* v2, float* out) {
  int t = threadIdx.x;
  int g = t & 7;
  int n = blockIdx.x * 32 + (t >> 3);
  int start = rp[n], end = rp[n + 1];
  float ad = ad2n[n];
  float num = 0.f, den = 0.f;
  for (int e = start + g; e < end; e += 8) {
    int s = colv[e];
    float2 tt = zs[s];
    float wi = __expf(leakyf(tt.x + ad));
    num += wi * tt.y;
    den += wi;
  }
  if (g == 0) {
    float2 self = zs[n];
    float w = __expf(leakyf(self.x + ad));
    num += w * self.y;
    den += w;
  }
  num += __shfl_xor(num, 1); den += __shfl_xor(den, 1);
  num += __shfl_xor(num, 2); den += __shfl_xor(den, 2);
  num += __shfl_xor(num, 4); den += __shfl_xor(den, 4);
  if (g == 0) {
    out[n] = num * __builtin_amdgcn_rcpf(den + 1e-16f) + v2[192];
    out[NN + n] = 0.f;
  }
}

extern "C" void kernel_launch(void* const* d_in, const int* in_sizes, int n_in,
                              void* d_out, int out_size, void* d_ws, size_t ws_size,
                              hipStream_t stream) {
  const float* x   = (const float*)d_in[0];
  const int*   ei  = (const int*)d_in[1];
  const float* We  = (const float*)d_in[2];
  const float* be  = (const float*)d_in[3];
  const float* bng = (const float*)d_in[4];
  const float* bnb = (const float*)d_in[5];
  const float* bnm = (const float*)d_in[6];
  const float* bnv = (const float*)d_in[7];
  const float* W1  = (const float*)d_in[8];
  const float* as1 = (const float*)d_in[9];
  const float* ad1 = (const float*)d_in[10];
  const float* b1  = (const float*)d_in[11];
  const float* W2  = (const float*)d_in[12];
  const float* as2 = (const float*)d_in[13];
  const float* ad2 = (const float*)d_in[14];
  const float* b2  = (const float*)d_in[15];
  const float* Wo  = (const float*)d_in[16];
  const float* bo  = (const float*)d_in[17];
  float* out = (float*)d_out;

  char* ws = (char*)d_ws;
  u16*    h1   = (u16*)(ws + OFF_H1);
  float*  as1n = (float*)(ws + OFF_AS1N);
  float*  ad1n = (float*)(ws + OFF_AD1N);
  float2* zs   = (float2*)(ws + OFF_ZS);
  float*  ad2n = (float*)(ws + OFF_AD2N);
  int*    rp   = (int*)(ws + OFF_RP);
  int*    wo   = (int*)(ws + OFF_WOFF);
  int*    colv = (int*)(ws + OFF_COL);
  float*  MP   = (float*)(ws + OFF_MP);
  float*  c1ac = (float*)(ws + OFF_C1AC);
  float*  v2   = (float*)(ws + OFF_V2);
  int*    bsum = (int*)(ws + OFF_BSUM);

  hipMemsetAsync(wo, 0, NN * sizeof(int), stream);
  count_fold_kernel<<<4138, 256, 0, stream>>>(ei, wo, W1, We, be, bng, bnb, bnm, bnv,
                                              as1, ad1, W2, as2, ad2, Wo, b2, bo,
                                              MP, c1ac, v2);
  scanA_kernel<<<NN / 1024, 1024, 0, stream>>>(wo, rp, bsum);
  scanB_kernel<<<1, 128, 0, stream>>>(bsum, rp);
  scanC_kernel<<<NN / 1024, 1024, 0, stream>>>(rp, bsum, wo);
  fill_gemm_kernel<<<4608, 256, 0, stream>>>(x, MP, h1, as1n, ad1n, ei, wo, colv);
  gat1_agg_kernel<<<NN / 4, 256, 0, stream>>>(rp, colv, as1n, ad1n, h1, b1, c1ac, v2, zs, ad2n);
  gat2_kernel<<<NN / 32, 256, 0, stream>>>(rp, colv, zs, ad2n, v2, out);
}

// Round 11
// 214.880 us; speedup vs baseline: 1.4836x; 1.2307x over previous
//
#include <hip/hip_runtime.h>
#include <hip/hip_bf16.h>

#define NN 131072
#define NE 1048576
#define INVLN2 1.44269504088896341f

typedef unsigned short u16;
typedef unsigned int u32;

__device__ __forceinline__ float bf2f(u16 u) {
  return __uint_as_float(((unsigned int)u) << 16);
}
__device__ __forceinline__ u16 f2bf(float f) {
  unsigned int u = __float_as_uint(f);
  unsigned int r = ((u >> 16) & 1u) + 0x7fffu;
  return (u16)((u + r) >> 16);
}
__device__ __forceinline__ float leakyf(float x) { return x >= 0.f ? x : 0.2f * x; }

// ---------------- workspace layout (bytes, all 16B-aligned) ----------------
constexpr size_t OFF_H1   = 0;                        // bf16 N*64 (raw)
constexpr size_t OFF_AS1N = 16777216;                 // f32 N*8 (raw, exp2 domain)
constexpr size_t OFF_AD1N = 20971520;                 // f32 N*8 (raw, exp2 domain)
constexpr size_t OFF_ZS   = 25165824;                 // float2 N {as2n(exp2), z}
constexpr size_t OFF_AD2N = 26214400;                 // f32 N (exp2 domain)
constexpr size_t OFF_RP   = 26738688;                 // int N+1
constexpr size_t OFF_WOFF = 27264000;                 // int N
constexpr size_t OFF_COL  = 27788288;                 // int E
constexpr size_t OFF_MP   = 31982592;                 // f32 M'[80][128]
constexpr size_t OFF_C1AC = 32023552;                 // f32 c1[64], ac[8]
constexpr size_t OFF_V2   = 32023840;                 // f32 va,vd,vz[64ea], cconst
constexpr size_t OFF_BSUM = 32024624;                 // int 128

// ---------------- scans ----------------
__global__ __launch_bounds__(1024) void scanA_kernel(const int* cnt, int* rp, int* bsum) {
  __shared__ int buf[1024];
  int t = threadIdx.x;
  int i = blockIdx.x * 1024 + t;
  int v = cnt[i];
  buf[t] = v;
  __syncthreads();
  for (int off = 1; off < 1024; off <<= 1) {
    int a = (t >= off) ? buf[t - off] : 0;
    __syncthreads();
    buf[t] += a;
    __syncthreads();
  }
  rp[i] = buf[t] - v;  // block-local exclusive
  if (t == 1023) bsum[blockIdx.x] = buf[t];
}
__global__ void scanB_kernel(int* bsum, int* rp) {
  __shared__ int buf[128];
  int t = threadIdx.x;
  int v = bsum[t];
  buf[t] = v;
  __syncthreads();
  for (int off = 1; off < 128; off <<= 1) {
    int a = (t >= off) ? buf[t - off] : 0;
    __syncthreads();
    buf[t] += a;
    __syncthreads();
  }
  bsum[t] = buf[t] - v;  // exclusive block offsets
  if (t == 127) rp[NN] = buf[127];
}
__global__ __launch_bounds__(1024) void scanC_kernel(int* rp, const int* bsum, int* wo) {
  int i = blockIdx.x * 1024 + threadIdx.x;
  int v = rp[i] + bsum[blockIdx.x];
  rp[i] = v;
  wo[i] = v;
}

// ======== fused: count (XCD-partitioned) || M'[80][128] fold || c1/ac || v2 ========
// blocks [0,4096): count; [4096,4136): M' rows; 4136: c1+ac; 4137: v2 (fold2).
__global__ __launch_bounds__(256) void count_fold_kernel(
    const int* __restrict__ ei, int* cnt, const float* W1, const float* We,
    const float* be, const float* bng, const float* bnb, const float* bnm,
    const float* bnv, const float* as1, const float* ad1, const float* W2,
    const float* as2, const float* ad2, const float* Wo, const float* b2,
    const float* bo, float* MP, float* c1ac, float* v2) {
  int b = blockIdx.x;
  int t = threadIdx.x;
  if (b < 4096) {
    // count: block only handles dst in partition b%8 (dst>>14). Prefetch all 8
    // dsts first (8 loads in flight), then fire the independent atomics.
    int p = b & 7;
    int base = (b >> 3) * 2048;
    int dsts[8];
#pragma unroll
    for (int j = 0; j < 8; ++j) dsts[j] = ei[NE + base + t + 256 * j];
#pragma unroll
    for (int j = 0; j < 8; ++j)
      if ((dsts[j] >> 14) == p) atomicAdd(&cnt[dsts[j]], 1);
  } else if (b < 4136) {
    // M' rows: M1 (rows<64) or A1/D1 (rows 64..79); A1/D1 scaled by 1/ln2 (exp2 domain)
    __shared__ float L[2][256];
    int mrow = b - 4096;
    int r0 = mrow * 2;
    int lr = t >> 7, k = t & 127;
    float sgc = bng[t] * rsqrtf(bnv[t] + 1e-5f);
#pragma unroll
    for (int q = 0; q < 2; ++q) {
      int r = r0 + q;
      float coef;
      if (r < 64) {
        coef = W1[r * 256 + t];
      } else if (r < 72) {
        int h = r - 64;
        coef = 0.f;
#pragma unroll
        for (int j = 0; j < 8; ++j) coef += as1[h * 8 + j] * W1[(h * 8 + j) * 256 + t];
        coef *= INVLN2;
      } else {
        int h = r - 72;
        coef = 0.f;
#pragma unroll
        for (int j = 0; j < 8; ++j) coef += ad1[h * 8 + j] * W1[(h * 8 + j) * 256 + t];
        coef *= INVLN2;
      }
      L[q][t] = coef * sgc;
    }
    __syncthreads();
    float acc = 0.f;
    for (int c = 0; c < 256; ++c) acc += L[lr][c] * We[c * 128 + k];
    MP[(size_t)(r0 + lr) * 128 + k] = acc;
  } else if (b == 4136) {
    // c1 = W1·ofs ; ac[h] = (1/ln2)·sum_j c1[h*8+j]*(as1+ad1)
    __shared__ float ofs[256];
    __shared__ float c1l[64];
    float sgc = bng[t] * rsqrtf(bnv[t] + 1e-5f);
    ofs[t] = (be[t] - bnm[t]) * sgc + bnb[t];
    __syncthreads();
    if (t < 64) {
      float a = 0.f;
      for (int c = 0; c < 256; ++c) a += W1[t * 256 + c] * ofs[c];
      c1ac[t] = a;
      c1l[t] = a;
    }
    __syncthreads();
    if (t < 8) {
      float s = 0.f;
#pragma unroll
      for (int j = 0; j < 8; ++j) s += c1l[t * 8 + j] * (as1[t * 8 + j] + ad1[t * 8 + j]);
      c1ac[64 + t] = s * INVLN2;
    }
  } else {
    // v2: va = (1/ln2)W2^T as2, vd = (1/ln2)W2^T ad2, vz = W2^T Wo, cconst = b2.Wo + bo
    __shared__ float pa[4][64], pd[4][64], pz[4][64];
    int k = t & 63, part = t >> 6;
    float a = 0.f, d = 0.f, z = 0.f;
    for (int c = part * 64; c < part * 64 + 64; ++c) {
      float w = W2[c * 64 + k];
      a += as2[c] * w;
      d += ad2[c] * w;
      z += Wo[c] * w;
    }
    pa[part][k] = a;
    pd[part][k] = d;
    pz[part][k] = z;
    __syncthreads();
    if (t < 64) {
      v2[t]       = (pa[0][t] + pa[1][t] + pa[2][t] + pa[3][t]) * INVLN2;
      v2[64 + t]  = (pd[0][t] + pd[1][t] + pd[2][t] + pd[3][t]) * INVLN2;
      v2[128 + t] = pz[0][t] + pz[1][t] + pz[2][t] + pz[3][t];
      float cc = b2[t] * Wo[t] + b2[64 + t] * Wo[64 + t] +
                 b2[128 + t] * Wo[128 + t] + b2[192 + t] * Wo[192 + t];
      for (int o = 1; o < 64; o <<= 1) cc += __shfl_xor(cc, o);
      if (t == 0) v2[192] = cc + bo[0];
    }
  }
}

// ======== fused: gemm_h1 (blocks 0..511, FIRST) || fill (blocks 512..4607) ========
// Round-8 ordering (best measured): gemm blocks dispatch first, fill backfills.
__global__ __launch_bounds__(256) void fill_gemm_kernel(const float* __restrict__ x,
                                                        const float* __restrict__ MP,
                                                        u16* __restrict__ h1,
                                                        float* __restrict__ as1n,
                                                        float* __restrict__ ad1n,
                                                        const int* __restrict__ ei,
                                                        int* wo, int* colv) {
  __shared__ float4 sM[80 * 32];
  int b = blockIdx.x;
  int t = threadIdx.x;
  if (b >= 512) {
    // ---- fill (XCD-partitioned): prefetch 8 edges, then 8 independent atomic chains ----
    int fb = b - 512;
    int p = fb & 7;
    int base = (fb >> 3) * 2048;
    int dsts[8], srcs[8];
#pragma unroll
    for (int j = 0; j < 8; ++j) {
      dsts[j] = ei[NE + base + t + 256 * j];
      srcs[j] = ei[base + t + 256 * j];
    }
#pragma unroll
    for (int j = 0; j < 8; ++j) {
      if ((dsts[j] >> 14) == p) {
        int pos = atomicAdd(&wo[dsts[j]], 1);
        colv[pos] = srcs[j];
      }
    }
    return;
  }
  // ---- gemm: h1' = x @ M'^T, M' = [M1;A1;D1] (80x128), LDS-broadcast M' ----
  int lane = t & 63, wv = t >> 6;
  const float4* MPv = (const float4*)MP;
  for (int i = t; i < 2560; i += 256) sM[i] = MPv[i];
  __syncthreads();
  int c0 = (wv & 1) * 40;  // col half
  size_t r0 = (size_t)b * 256 + (wv >> 1) * 128 + lane;  // rows r0, r0+64
  const float4* x0 = (const float4*)(x + r0 * 128);
  const float4* x1 = (const float4*)(x + (r0 + 64) * 128);
  float a0[40], a1[40];
#pragma unroll
  for (int c = 0; c < 40; ++c) { a0[c] = 0.f; a1[c] = 0.f; }
  for (int q = 0; q < 32; ++q) {
    float4 cx0 = x0[q];
    float4 cx1 = x1[q];
    const float4* mp = sM + c0 * 32 + q;
#pragma unroll
    for (int c = 0; c < 40; ++c) {
      float4 B = mp[c * 32];
      a0[c] += cx0.x * B.x; a0[c] += cx0.y * B.y;
      a0[c] += cx0.z * B.z; a0[c] += cx0.w * B.w;
      a1[c] += cx1.x * B.x; a1[c] += cx1.y * B.y;
      a1[c] += cx1.z * B.z; a1[c] += cx1.w * B.w;
    }
  }
#pragma unroll
  for (int rr = 0; rr < 2; ++rr) {
    size_t row = r0 + rr * 64;
    if (c0 == 0) {
      u32 ux[20];
#pragma unroll
      for (int j = 0; j < 20; ++j) {
        float lo = rr ? a1[2 * j] : a0[2 * j];
        float hi = rr ? a1[2 * j + 1] : a0[2 * j + 1];
        ux[j] = (u32)f2bf(lo) | ((u32)f2bf(hi) << 16);
      }
      uint4* dst = (uint4*)(h1 + row * 64);
#pragma unroll
      for (int j = 0; j < 5; ++j)
        dst[j] = make_uint4(ux[4 * j], ux[4 * j + 1], ux[4 * j + 2], ux[4 * j + 3]);
    } else {
      u32 ux[12];
#pragma unroll
      for (int j = 0; j < 12; ++j) {
        float lo = rr ? a1[2 * j] : a0[2 * j];
        float hi = rr ? a1[2 * j + 1] : a0[2 * j + 1];
        ux[j] = (u32)f2bf(lo) | ((u32)f2bf(hi) << 16);
      }
      uint4* dst = (uint4*)(h1 + row * 64 + 40);
#pragma unroll
      for (int j = 0; j < 3; ++j)
        dst[j] = make_uint4(ux[4 * j], ux[4 * j + 1], ux[4 * j + 2], ux[4 * j + 3]);
      float4* as4 = (float4*)(as1n + row * 8);
      float4* ad4 = (float4*)(ad1n + row * 8);
      if (rr == 0) {
        as4[0] = make_float4(a0[24], a0[25], a0[26], a0[27]);
        as4[1] = make_float4(a0[28], a0[29], a0[30], a0[31]);
        ad4[0] = make_float4(a0[32], a0[33], a0[34], a0[35]);
        ad4[1] = make_float4(a0[36], a0[37], a0[38], a0[39]);
      } else {
        as4[0] = make_float4(a1[24], a1[25], a1[26], a1[27]);
        as4[1] = make_float4(a1[28], a1[29], a1[30], a1[31]);
        ad4[0] = make_float4(a1[32], a1[33], a1[34], a1[35]);
        ad4[1] = make_float4(a1[36], a1[37], a1[38], a1[39]);
      }
    }
  }
}

// ------ GAT1 aggregation + ELU + fused GAT2 node scalars (packed-pair form) ------
// Attention logits are in exp2 domain (A1/D1/ac pre-scaled by 1/ln2):
// weight = exp2(leaky(logit)) — bare v_exp_f32, no pre-multiply.
__global__ __launch_bounds__(256) void gat1_agg_kernel(const int* __restrict__ rp,
                                                       const int* __restrict__ colv,
                                                       const float* __restrict__ as1n,
                                                       const float* __restrict__ ad1n,
                                                       const u16* __restrict__ h1,
                                                       const float* b1,
                                                       const float* __restrict__ c1ac,
                                                       const float* v2,
                                                       float2* zs, float* ad2n) {
  __shared__ float wlds[4][64];
  __shared__ int slds[4][8];
  int t = threadIdx.x, lane = t & 63, wv = t >> 6;
  int n = blockIdx.x * 4 + wv;
  int m = lane & 31;    // channel pair (2m, 2m+1)
  int half = lane >> 5; // edge parity this lane accumulates
  int hh = m >> 2;      // head of channels 2m,2m+1
  int h1i = lane & 7;   // phase-1 head
  int e8 = lane >> 3;   // phase-1 edge slot
  int start = rp[n], end = rp[n + 1];
  const char* h1b = (const char*)h1;
  float adh = ad1n[(size_t)n * 8 + hh] + c1ac[64 + hh];
  float ws = exp2f(leakyf(as1n[(size_t)n * 8 + hh] + adh));
  float denom = ws;
  u32 sv = *(const u32*)(h1b + ((size_t)n << 7) + m * 4);
  float wsel = half ? 0.f : ws;  // self-loop only in half 0
  float acc0 = wsel * __uint_as_float(sv << 16);
  float acc1 = wsel * __uint_as_float(sv & 0xffff0000u);
  float ad_p1 = ad1n[(size_t)n * 8 + h1i] + c1ac[64 + h1i];  // phase-1 layout
  for (int base = start; base < end; base += 8) {
    int mm = end - base;
    if (mm > 8) mm = 8;
    // ---- phase 1: weights for 8 edges x 8 heads ----
    int eidx = base + e8;
    int ecl = (eidx < end) ? eidx : (end - 1);
    int s = colv[ecl];
    float w = (e8 < mm) ? exp2f(leakyf(as1n[(size_t)s * 8 + h1i] + ad_p1)) : 0.f;
    if (h1i == 0) slds[wv][e8] = s;
    wlds[wv][lane] = w;
    float dsum = w;
    dsum += __shfl_xor(dsum, 8);
    dsum += __shfl_xor(dsum, 16);
    dsum += __shfl_xor(dsum, 32);
    denom += __shfl(dsum, hh);
    // ---- phase 2: 2 edges per iteration (half 0: even, half 1: odd) ----
#pragma unroll
    for (int i = 0; i < 4; ++i) {
      int e = 2 * i + half;
      float wi = wlds[wv][e * 8 + hh];
      int si = slds[wv][e];
      u32 v = *(const u32*)(h1b + ((size_t)si << 7) + m * 4);
      acc0 += wi * __uint_as_float(v << 16);
      acc1 += wi * __uint_as_float(v & 0xffff0000u);
    }
  }
  acc0 += __shfl_xor(acc0, 32);
  acc1 += __shfl_xor(acc1, 32);
  float dinv = __builtin_amdgcn_rcpf(denom + 1e-16f);
  float2 c1p = ((const float2*)c1ac)[m];
  float2 b1p = ((const float2*)b1)[m];
  float v0 = acc0 * dinv + c1p.x + b1p.x;
  float v1 = acc1 * dinv + c1p.y + b1p.y;
  v0 = v0 > 0.f ? v0 : __expf(v0) - 1.f;  // ELU
  v1 = v1 > 0.f ? v1 : __expf(v1) - 1.f;
  float2 vap = ((const float2*)v2)[m];
  float2 vdp = ((const float2*)(v2 + 64))[m];
  float2 vzp = ((const float2*)(v2 + 128))[m];
  float p0 = v0 * vap.x + v1 * vap.y;
  float p1 = v0 * vdp.x + v1 * vdp.y;
  float p2 = v0 * vzp.x + v1 * vzp.y;
  for (int o = 1; o < 32; o <<= 1) {
    p0 += __shfl_xor(p0, o);
    p1 += __shfl_xor(p1, o);
    p2 += __shfl_xor(p2, o);
  }
  if (lane == 0) {
    zs[n] = make_float2(p0, p2);
    ad2n[n] = p1;
  }
}

// ------- GAT2 scalar aggregation: 8 lanes per node (exp2-domain logits) -------
__global__ __launch_bounds__(256) void gat2_kernel(const int* __restrict__ rp,
                                                   const int* __restrict__ colv,
                                                   const float2* __restrict__ zs,
                                                   const float* __restrict__ ad2n,
                                                   const float* v2, float* out) {
  int t = threadIdx.x;
  int g = t & 7;
  int n = blockIdx.x * 32 + (t >> 3);
  int start = rp[n], end = rp[n + 1];
  float ad = ad2n[n];
  float num = 0.f, den = 0.f;
  for (int e = start + g; e < end; e += 8) {
    int s = colv[e];
    float2 tt = zs[s];
    float wi = exp2f(leakyf(tt.x + ad));
    num += wi * tt.y;
    den += wi;
  }
  if (g == 0) {
    float2 self = zs[n];
    float w = exp2f(leakyf(self.x + ad));
    num += w * self.y;
    den += w;
  }
  num += __shfl_xor(num, 1); den += __shfl_xor(den, 1);
  num += __shfl_xor(num, 2); den += __shfl_xor(den, 2);
  num += __shfl_xor(num, 4); den += __shfl_xor(den, 4);
  if (g == 0) {
    out[n] = num * __builtin_amdgcn_rcpf(den + 1e-16f) + v2[192];
    out[NN + n] = 0.f;
  }
}

extern "C" void kernel_launch(void* const* d_in, const int* in_sizes, int n_in,
                              void* d_out, int out_size, void* d_ws, size_t ws_size,
                              hipStream_t stream) {
  const float* x   = (const float*)d_in[0];
  const int*   ei  = (const int*)d_in[1];
  const float* We  = (const float*)d_in[2];
  const float* be  = (const float*)d_in[3];
  const float* bng = (const float*)d_in[4];
  const float* bnb = (const float*)d_in[5];
  const float* bnm = (const float*)d_in[6];
  const float* bnv = (const float*)d_in[7];
  const float* W1  = (const float*)d_in[8];
  const float* as1 = (const float*)d_in[9];
  const float* ad1 = (const float*)d_in[10];
  const float* b1  = (const float*)d_in[11];
  const float* W2  = (const float*)d_in[12];
  const float* as2 = (const float*)d_in[13];
  const float* ad2 = (const float*)d_in[14];
  const float* b2  = (const float*)d_in[15];
  const float* Wo  = (const float*)d_in[16];
  const float* bo  = (const float*)d_in[17];
  float* out = (float*)d_out;

  char* ws = (char*)d_ws;
  u16*    h1   = (u16*)(ws + OFF_H1);
  float*  as1n = (float*)(ws + OFF_AS1N);
  float*  ad1n = (float*)(ws + OFF_AD1N);
  float2* zs   = (float2*)(ws + OFF_ZS);
  float*  ad2n = (float*)(ws + OFF_AD2N);
  int*    rp   = (int*)(ws + OFF_RP);
  int*    wo   = (int*)(ws + OFF_WOFF);
  int*    colv = (int*)(ws + OFF_COL);
  float*  MP   = (float*)(ws + OFF_MP);
  float*  c1ac = (float*)(ws + OFF_C1AC);
  float*  v2   = (float*)(ws + OFF_V2);
  int*    bsum = (int*)(ws + OFF_BSUM);

  hipMemsetAsync(wo, 0, NN * sizeof(int), stream);
  count_fold_kernel<<<4138, 256, 0, stream>>>(ei, wo, W1, We, be, bng, bnb, bnm, bnv,
                                              as1, ad1, W2, as2, ad2, Wo, b2, bo,
                                              MP, c1ac, v2);
  scanA_kernel<<<NN / 1024, 1024, 0, stream>>>(wo, rp, bsum);
  scanB_kernel<<<1, 128, 0, stream>>>(bsum, rp);
  scanC_kernel<<<NN / 1024, 1024, 0, stream>>>(rp, bsum, wo);
  fill_gemm_kernel<<<4608, 256, 0, stream>>>(x, MP, h1, as1n, ad1n, ei, wo, colv);
  gat1_agg_kernel<<<NN / 4, 256, 0, stream>>>(rp, colv, as1n, ad1n, h1, b1, c1ac, v2, zs, ad2n);
  gat2_kernel<<<NN / 32, 256, 0, stream>>>(rp, colv, zs, ad2n, v2, out);
}

// Round 12
// 187.197 us; speedup vs baseline: 1.7030x; 1.1479x over previous
//
#include <hip/hip_runtime.h>
#include <hip/hip_bf16.h>

#define NN 131072
#define NE 1048576
#define CAP 48
#define INVLN2 1.44269504088896341f

typedef unsigned short u16;
typedef unsigned int u32;

__device__ __forceinline__ float bf2f(u16 u) {
  return __uint_as_float(((unsigned int)u) << 16);
}
__device__ __forceinline__ u16 f2bf(float f) {
  unsigned int u = __float_as_uint(f);
  unsigned int r = ((u >> 16) & 1u) + 0x7fffu;
  return (u16)((u + r) >> 16);
}
__device__ __forceinline__ float leakyf(float x) { return x >= 0.f ? x : 0.2f * x; }

// ---------------- workspace layout (bytes, 16B-aligned) ----------------
constexpr size_t OFF_H1   = 0;                        // bf16 N*64 (raw)
constexpr size_t OFF_AS1N = 16777216;                 // f32 N*8 (exp2 domain)
constexpr size_t OFF_AD1N = 20971520;                 // f32 N*8 (exp2 domain)
constexpr size_t OFF_ZS   = 25165824;                 // float2 N {as2n, z}
constexpr size_t OFF_AD2N = 26214400;                 // f32 N
constexpr size_t OFF_CNT  = 26738688;                 // int N (degree)
constexpr size_t OFF_COL  = 27262976;                 // int N*CAP (bucketed adj)
constexpr size_t OFF_MP   = 52428800;                 // f32 M'[80][128]
constexpr size_t OFF_C1AC = 52469760;                 // f32 c1[64], ac[8]
constexpr size_t OFF_V2   = 52470064;                 // f32 va,vd,vz[64ea], cconst

// ======== K1: bucket-fill half 1 (blocks 0..2047) || folds (2048..2089) ========
__global__ __launch_bounds__(256) void fill1_fold_kernel(
    const int* __restrict__ ei, int* cnt, int* colv, const float* W1, const float* We,
    const float* be, const float* bng, const float* bnb, const float* bnm,
    const float* bnv, const float* as1, const float* ad1, const float* W2,
    const float* as2, const float* ad2, const float* Wo, const float* b2,
    const float* bo, float* MP, float* c1ac, float* v2) {
  int b = blockIdx.x;
  int t = threadIdx.x;
  if (b < 2048) {
    // bucket-fill, XCD-partitioned (partition p = dst>>14 handled by blocks b&7==p,
    // which land on XCD p). Prefetch 8 edges -> 8 independent atomic chains.
    int p = b & 7;
    int base = (b >> 3) * 2048;
    int dsts[8], srcs[8];
#pragma unroll
    for (int j = 0; j < 8; ++j) {
      dsts[j] = ei[NE + base + t + 256 * j];
      srcs[j] = ei[base + t + 256 * j];
    }
#pragma unroll
    for (int j = 0; j < 8; ++j) {
      if ((dsts[j] >> 14) == p) {
        int slot = atomicAdd(&cnt[dsts[j]], 1);
        colv[dsts[j] * CAP + slot] = srcs[j];
      }
    }
  } else if (b < 2088) {
    // M' rows: M1 (rows<64) or A1/D1 (rows 64..79, 1/ln2-scaled for exp2 domain)
    __shared__ float L[2][256];
    int mrow = b - 2048;
    int r0 = mrow * 2;
    int lr = t >> 7, k = t & 127;
    float sgc = bng[t] * rsqrtf(bnv[t] + 1e-5f);
#pragma unroll
    for (int q = 0; q < 2; ++q) {
      int r = r0 + q;
      float coef;
      if (r < 64) {
        coef = W1[r * 256 + t];
      } else if (r < 72) {
        int h = r - 64;
        coef = 0.f;
#pragma unroll
        for (int j = 0; j < 8; ++j) coef += as1[h * 8 + j] * W1[(h * 8 + j) * 256 + t];
        coef *= INVLN2;
      } else {
        int h = r - 72;
        coef = 0.f;
#pragma unroll
        for (int j = 0; j < 8; ++j) coef += ad1[h * 8 + j] * W1[(h * 8 + j) * 256 + t];
        coef *= INVLN2;
      }
      L[q][t] = coef * sgc;
    }
    __syncthreads();
    float acc = 0.f;
    for (int c = 0; c < 256; ++c) acc += L[lr][c] * We[c * 128 + k];
    MP[(size_t)(r0 + lr) * 128 + k] = acc;
  } else if (b == 2088) {
    // c1 = W1·ofs ; ac[h] = (1/ln2)·sum_j c1[h*8+j]*(as1+ad1)
    __shared__ float ofs[256];
    __shared__ float c1l[64];
    float sgc = bng[t] * rsqrtf(bnv[t] + 1e-5f);
    ofs[t] = (be[t] - bnm[t]) * sgc + bnb[t];
    __syncthreads();
    if (t < 64) {
      float a = 0.f;
      for (int c = 0; c < 256; ++c) a += W1[t * 256 + c] * ofs[c];
      c1ac[t] = a;
      c1l[t] = a;
    }
    __syncthreads();
    if (t < 8) {
      float s = 0.f;
#pragma unroll
      for (int j = 0; j < 8; ++j) s += c1l[t * 8 + j] * (as1[t * 8 + j] + ad1[t * 8 + j]);
      c1ac[64 + t] = s * INVLN2;
    }
  } else {
    // v2: va/vd (1/ln2-scaled), vz, cconst = b2.Wo + bo
    __shared__ float pa[4][64], pd[4][64], pz[4][64];
    int k = t & 63, part = t >> 6;
    float a = 0.f, d = 0.f, z = 0.f;
    for (int c = part * 64; c < part * 64 + 64; ++c) {
      float w = W2[c * 64 + k];
      a += as2[c] * w;
      d += ad2[c] * w;
      z += Wo[c] * w;
    }
    pa[part][k] = a;
    pd[part][k] = d;
    pz[part][k] = z;
    __syncthreads();
    if (t < 64) {
      v2[t]       = (pa[0][t] + pa[1][t] + pa[2][t] + pa[3][t]) * INVLN2;
      v2[64 + t]  = (pd[0][t] + pd[1][t] + pd[2][t] + pd[3][t]) * INVLN2;
      v2[128 + t] = pz[0][t] + pz[1][t] + pz[2][t] + pz[3][t];
      float cc = b2[t] * Wo[t] + b2[64 + t] * Wo[64 + t] +
                 b2[128 + t] * Wo[128 + t] + b2[192 + t] * Wo[192 + t];
      for (int o = 1; o < 64; o <<= 1) cc += __shfl_xor(cc, o);
      if (t == 0) v2[192] = cc + bo[0];
    }
  }
}

// ======== K2: gemm_h1 (blocks 0..511, FIRST) || bucket-fill half 2 (512..2559) ========
__global__ __launch_bounds__(256) void gemm_fill2_kernel(const float* __restrict__ x,
                                                         const float* __restrict__ MP,
                                                         u16* __restrict__ h1,
                                                         float* __restrict__ as1n,
                                                         float* __restrict__ ad1n,
                                                         const int* __restrict__ ei,
                                                         int* cnt, int* colv) {
  __shared__ float4 sM[80 * 32];
  int b = blockIdx.x;
  int t = threadIdx.x;
  if (b >= 512) {
    int fb = b - 512;
    int p = fb & 7;
    int base = NE / 2 + (fb >> 3) * 2048;
    int dsts[8], srcs[8];
#pragma unroll
    for (int j = 0; j < 8; ++j) {
      dsts[j] = ei[NE + base + t + 256 * j];
      srcs[j] = ei[base + t + 256 * j];
    }
#pragma unroll
    for (int j = 0; j < 8; ++j) {
      if ((dsts[j] >> 14) == p) {
        int slot = atomicAdd(&cnt[dsts[j]], 1);
        colv[dsts[j] * CAP + slot] = srcs[j];
      }
    }
    return;
  }
  // ---- gemm: h1' = x @ M'^T, M' = [M1;A1;D1] (80x128), LDS-broadcast M' ----
  int lane = t & 63, wv = t >> 6;
  const float4* MPv = (const float4*)MP;
  for (int i = t; i < 2560; i += 256) sM[i] = MPv[i];
  __syncthreads();
  int c0 = (wv & 1) * 40;  // col half
  size_t r0 = (size_t)b * 256 + (wv >> 1) * 128 + lane;  // rows r0, r0+64
  const float4* x0 = (const float4*)(x + r0 * 128);
  const float4* x1 = (const float4*)(x + (r0 + 64) * 128);
  float a0[40], a1[40];
#pragma unroll
  for (int c = 0; c < 40; ++c) { a0[c] = 0.f; a1[c] = 0.f; }
  for (int q = 0; q < 32; ++q) {
    float4 cx0 = x0[q];
    float4 cx1 = x1[q];
    const float4* mp = sM + c0 * 32 + q;
#pragma unroll
    for (int c = 0; c < 40; ++c) {
      float4 B = mp[c * 32];
      a0[c] += cx0.x * B.x; a0[c] += cx0.y * B.y;
      a0[c] += cx0.z * B.z; a0[c] += cx0.w * B.w;
      a1[c] += cx1.x * B.x; a1[c] += cx1.y * B.y;
      a1[c] += cx1.z * B.z; a1[c] += cx1.w * B.w;
    }
  }
#pragma unroll
  for (int rr = 0; rr < 2; ++rr) {
    size_t row = r0 + rr * 64;
    if (c0 == 0) {
      u32 ux[20];
#pragma unroll
      for (int j = 0; j < 20; ++j) {
        float lo = rr ? a1[2 * j] : a0[2 * j];
        float hi = rr ? a1[2 * j + 1] : a0[2 * j + 1];
        ux[j] = (u32)f2bf(lo) | ((u32)f2bf(hi) << 16);
      }
      uint4* dst = (uint4*)(h1 + row * 64);
#pragma unroll
      for (int j = 0; j < 5; ++j)
        dst[j] = make_uint4(ux[4 * j], ux[4 * j + 1], ux[4 * j + 2], ux[4 * j + 3]);
    } else {
      u32 ux[12];
#pragma unroll
      for (int j = 0; j < 12; ++j) {
        float lo = rr ? a1[2 * j] : a0[2 * j];
        float hi = rr ? a1[2 * j + 1] : a0[2 * j + 1];
        ux[j] = (u32)f2bf(lo) | ((u32)f2bf(hi) << 16);
      }
      uint4* dst = (uint4*)(h1 + row * 64 + 40);
#pragma unroll
      for (int j = 0; j < 3; ++j)
        dst[j] = make_uint4(ux[4 * j], ux[4 * j + 1], ux[4 * j + 2], ux[4 * j + 3]);
      float4* as4 = (float4*)(as1n + row * 8);
      float4* ad4 = (float4*)(ad1n + row * 8);
      if (rr == 0) {
        as4[0] = make_float4(a0[24], a0[25], a0[26], a0[27]);
        as4[1] = make_float4(a0[28], a0[29], a0[30], a0[31]);
        ad4[0] = make_float4(a0[32], a0[33], a0[34], a0[35]);
        ad4[1] = make_float4(a0[36], a0[37], a0[38], a0[39]);
      } else {
        as4[0] = make_float4(a1[24], a1[25], a1[26], a1[27]);
        as4[1] = make_float4(a1[28], a1[29], a1[30], a1[31]);
        ad4[0] = make_float4(a1[32], a1[33], a1[34], a1[35]);
        ad4[1] = make_float4(a1[36], a1[37], a1[38], a1[39]);
      }
    }
  }
}

// ------ GAT1 aggregation + ELU + fused GAT2 node scalars (packed-pair form) ------
// Denominator accumulated per-lane in phase 2 (no per-chunk shuffle chain).
__global__ __launch_bounds__(256) void gat1_agg_kernel(const int* __restrict__ cnt,
                                                       const int* __restrict__ colv,
                                                       const float* __restrict__ as1n,
                                                       const float* __restrict__ ad1n,
                                                       const u16* __restrict__ h1,
                                                       const float* b1,
                                                       const float* __restrict__ c1ac,
                                                       const float* v2,
                                                       float2* zs, float* ad2n) {
  __shared__ float wlds[4][64];
  __shared__ int slds[4][8];
  int t = threadIdx.x, lane = t & 63, wv = t >> 6;
  int n = blockIdx.x * 4 + wv;
  int m = lane & 31;    // channel pair (2m, 2m+1)
  int half = lane >> 5; // edge parity this lane accumulates
  int hh = m >> 2;      // head of channels 2m,2m+1
  int h1i = lane & 7;   // phase-1 head
  int e8 = lane >> 3;   // phase-1 edge slot
  int start = n * CAP;
  int end = start + cnt[n];
  const char* h1b = (const char*)h1;
  float adh = ad1n[(size_t)n * 8 + hh] + c1ac[64 + hh];
  float ws = exp2f(leakyf(as1n[(size_t)n * 8 + hh] + adh));
  u32 sv = *(const u32*)(h1b + ((size_t)n << 7) + m * 4);
  float wsel = half ? 0.f : ws;  // self-loop only in half 0
  float acc0 = wsel * __uint_as_float(sv << 16);
  float acc1 = wsel * __uint_as_float(sv & 0xffff0000u);
  float dd = 0.f;  // per-lane denom partial (this parity, head hh)
  float ad_p1 = ad1n[(size_t)n * 8 + h1i] + c1ac[64 + h1i];  // phase-1 layout
  for (int base = start; base < end; base += 8) {
    int mm = end - base;
    if (mm > 8) mm = 8;
    // ---- phase 1: weights for 8 edges x 8 heads (no reduction) ----
    int eidx = base + e8;
    int ecl = (eidx < end) ? eidx : (end - 1);
    int s = colv[ecl];
    float w = (e8 < mm) ? exp2f(leakyf(as1n[(size_t)s * 8 + h1i] + ad_p1)) : 0.f;
    if (h1i == 0) slds[wv][e8] = s;
    wlds[wv][lane] = w;
    // ---- phase 2: 2 edges per iteration (half 0: even, half 1: odd) ----
#pragma unroll
    for (int i = 0; i < 4; ++i) {
      int e = 2 * i + half;
      float wi = wlds[wv][e * 8 + hh];
      int si = slds[wv][e];
      u32 v = *(const u32*)(h1b + ((size_t)si << 7) + m * 4);
      dd += wi;
      acc0 += wi * __uint_as_float(v << 16);
      acc1 += wi * __uint_as_float(v & 0xffff0000u);
    }
  }
  // merge parities: acc + denom partials
  acc0 += __shfl_xor(acc0, 32);
  acc1 += __shfl_xor(acc1, 32);
  dd += __shfl_xor(dd, 32);
  float denom = ws + dd;
  float dinv = __builtin_amdgcn_rcpf(denom + 1e-16f);
  float2 c1p = ((const float2*)c1ac)[m];
  float2 b1p = ((const float2*)b1)[m];
  float v0 = acc0 * dinv + c1p.x + b1p.x;
  float v1 = acc1 * dinv + c1p.y + b1p.y;
  v0 = v0 > 0.f ? v0 : __expf(v0) - 1.f;  // ELU
  v1 = v1 > 0.f ? v1 : __expf(v1) - 1.f;
  float2 vap = ((const float2*)v2)[m];
  float2 vdp = ((const float2*)(v2 + 64))[m];
  float2 vzp = ((const float2*)(v2 + 128))[m];
  float p0 = v0 * vap.x + v1 * vap.y;
  float p1 = v0 * vdp.x + v1 * vdp.y;
  float p2 = v0 * vzp.x + v1 * vzp.y;
  for (int o = 1; o < 32; o <<= 1) {
    p0 += __shfl_xor(p0, o);
    p1 += __shfl_xor(p1, o);
    p2 += __shfl_xor(p2, o);
  }
  if (lane == 0) {
    zs[n] = make_float2(p0, p2);
    ad2n[n] = p1;
  }
}

// ------- GAT2 scalar aggregation: 8 lanes per node (exp2-domain logits) -------
__global__ __launch_bounds__(256) void gat2_kernel(const int* __restrict__ cnt,
                                                   const int* __restrict__ colv,
                                                   const float2* __restrict__ zs,
                                                   const float* __restrict__ ad2n,
                                                   const float* v2, float* out) {
  int t = threadIdx.x;
  int g = t & 7;
  int n = blockIdx.x * 32 + (t >> 3);
  int start = n * CAP;
  int end = start + cnt[n];
  float ad = ad2n[n];
  float num = 0.f, den = 0.f;
  for (int e = start + g; e < end; e += 8) {
    int s = colv[e];
    float2 tt = zs[s];
    float wi = exp2f(leakyf(tt.x + ad));
    num += wi * tt.y;
    den += wi;
  }
  if (g == 0) {
    float2 self = zs[n];
    float w = exp2f(leakyf(self.x + ad));
    num += w * self.y;
    den += w;
  }
  num += __shfl_xor(num, 1); den += __shfl_xor(den, 1);
  num += __shfl_xor(num, 2); den += __shfl_xor(den, 2);
  num += __shfl_xor(num, 4); den += __shfl_xor(den, 4);
  if (g == 0) {
    out[n] = num * __builtin_amdgcn_rcpf(den + 1e-16f) + v2[192];
    out[NN + n] = 0.f;
  }
}

extern "C" void kernel_launch(void* const* d_in, const int* in_sizes, int n_in,
                              void* d_out, int out_size, void* d_ws, size_t ws_size,
                              hipStream_t stream) {
  const float* x   = (const float*)d_in[0];
  const int*   ei  = (const int*)d_in[1];
  const float* We  = (const float*)d_in[2];
  const float* be  = (const float*)d_in[3];
  const float* bng = (const float*)d_in[4];
  const float* bnb = (const float*)d_in[5];
  const float* bnm = (const float*)d_in[6];
  const float* bnv = (const float*)d_in[7];
  const float* W1  = (const float*)d_in[8];
  const float* as1 = (const float*)d_in[9];
  const float* ad1 = (const float*)d_in[10];
  const float* b1  = (const float*)d_in[11];
  const float* W2  = (const float*)d_in[12];
  const float* as2 = (const float*)d_in[13];
  const float* ad2 = (const float*)d_in[14];
  const float* b2  = (const float*)d_in[15];
  const float* Wo  = (const float*)d_in[16];
  const float* bo  = (const float*)d_in[17];
  float* out = (float*)d_out;

  char* ws = (char*)d_ws;
  u16*    h1   = (u16*)(ws + OFF_H1);
  float*  as1n = (float*)(ws + OFF_AS1N);
  float*  ad1n = (float*)(ws + OFF_AD1N);
  float2* zs   = (float2*)(ws + OFF_ZS);
  float*  ad2n = (float*)(ws + OFF_AD2N);
  int*    cnt  = (int*)(ws + OFF_CNT);
  int*    colv = (int*)(ws + OFF_COL);
  float*  MP   = (float*)(ws + OFF_MP);
  float*  c1ac = (float*)(ws + OFF_C1AC);
  float*  v2   = (float*)(ws + OFF_V2);

  hipMemsetAsync(cnt, 0, NN * sizeof(int), stream);
  fill1_fold_kernel<<<2090, 256, 0, stream>>>(ei, cnt, colv, W1, We, be, bng, bnb,
                                              bnm, bnv, as1, ad1, W2, as2, ad2, Wo,
                                              b2, bo, MP, c1ac, v2);
  gemm_fill2_kernel<<<2560, 256, 0, stream>>>(x, MP, h1, as1n, ad1n, ei, cnt, colv);
  gat1_agg_kernel<<<NN / 4, 256, 0, stream>>>(cnt, colv, as1n, ad1n, h1, b1, c1ac, v2, zs, ad2n);
  gat2_kernel<<<NN / 32, 256, 0, stream>>>(cnt, colv, zs, ad2n, v2, out);
}